// Round 8
// baseline (1418.381 us; speedup 1.0000x reference)
//
#include <hip/hip_runtime.h>
#include <hip/hip_bf16.h>
#include <float.h>
#include <math.h>

typedef __hip_bfloat16 bf16;

#define NEGBIG (-1e30f)

__device__ __forceinline__ float ldv(const bf16* p, int i) { return __bfloat162float(p[i]); }
__device__ __forceinline__ float ldv(const float* p, int i) { return p[i]; }
__device__ __forceinline__ void stv(float* p, int i, float v) { p[i] = v; }
__device__ __forceinline__ void stv(bf16* p, int i, float v) { p[i] = __float2bfloat16(v); }

__device__ __forceinline__ float wave_sum(float v) {
#pragma unroll
  for (int off = 32; off; off >>= 1) v += __shfl_xor(v, off, 64);
  return v;
}
__device__ __forceinline__ float wave_max(float v) {
#pragma unroll
  for (int off = 32; off; off >>= 1) v = fmaxf(v, __shfl_xor(v, off, 64));
  return v;
}

// ---------------- generic tiled GEMM: C(MxN) = A(MxK) @ B(KxN), f32 accum ----
template <typename TA, typename TB, typename TC>
__global__ __launch_bounds__(256) void gemm_tile(
    const TA* __restrict__ A, const TB* __restrict__ B, TC* __restrict__ C,
    int M, int N, int K, int lda, int ldb, int ldc)
{
  __shared__ float As[16][65];
  __shared__ float Bs[16][65];
  const int tid = threadIdx.x;
  const int tx = tid & 15, ty = tid >> 4;
  const int row0 = blockIdx.y * 64, col0 = blockIdx.x * 64;
  float acc[4][4] = {};
  for (int k0 = 0; k0 < K; k0 += 16) {
#pragma unroll
    for (int l = 0; l < 4; ++l) {
      int idx = tid + l * 256;
      int m = idx >> 4, kk = idx & 15;
      As[kk][m] = ldv(A, (row0 + m) * lda + k0 + kk);
      int kk2 = idx >> 6, n = idx & 63;
      Bs[kk2][n] = ldv(B, (k0 + kk2) * ldb + col0 + n);
    }
    __syncthreads();
#pragma unroll
    for (int kk = 0; kk < 16; ++kk) {
      float a[4], b[4];
#pragma unroll
      for (int i = 0; i < 4; ++i) a[i] = As[kk][ty * 4 + i];
#pragma unroll
      for (int j = 0; j < 4; ++j) b[j] = Bs[kk][tx * 4 + j];
#pragma unroll
      for (int i = 0; i < 4; ++i)
#pragma unroll
        for (int j = 0; j < 4; ++j) acc[i][j] += a[i] * b[j];
    }
    __syncthreads();
  }
#pragma unroll
  for (int i = 0; i < 4; ++i)
#pragma unroll
    for (int j = 0; j < 4; ++j)
      stv(C, (row0 + ty * 4 + i) * ldc + col0 + tx * 4 + j, acc[i][j]);
}

// ---------------- RoPE (first 32 dims) + RMSNorm, one wave per 64-dim row ----
__global__ __launch_bounds__(256) void rope_rms_kernel(
    float* __restrict__ x, const float* __restrict__ g, int rows, int posShift)
{
  const int lane = threadIdx.x & 63;
  const int wid = threadIdx.x >> 6;
  const int r = blockIdx.x * 4 + wid;
  if (r >= rows) return;
  const int pos = r >> posShift;
  float val = x[r * 64 + lane];
  float p = __shfl_xor(val, 16, 64);
  float out = val;
  if (lane < 32) {
    int i = lane & 15;
    double ang = (double)pos * pow(10000.0, -(double)i / 16.0);
    float cc = (float)cos(ang), ss = (float)sin(ang);
    out = (lane < 16) ? (val * cc - p * ss) : (p * ss + val * cc);
  }
  float ms = wave_sum(out * out) * (1.0f / 64.0f);
  float rn = rsqrtf(ms + 1e-6f);
  x[r * 64 + lane] = out * rn * ldv(g, lane);
}

// ---------------- block-mean compression: kc/vc (64 blocks x 64 dims) --------
__global__ void compress_kernel(const float* __restrict__ k, const float* __restrict__ v,
                                float* __restrict__ kc, float* __restrict__ vc)
{
  const int n = blockIdx.x;   // block index 0..63
  const int d = threadIdx.x;  // dim 0..63
  float sk = 0.f, sv = 0.f;
  for (int j = 0; j < 32; ++j) {
    sk += k[(n * 32 + j) * 64 + d];
    sv += v[(n * 32 + j) * 64 + d];
  }
  kc[n * 64 + d] = sk * (1.0f / 32.0f);
  vc[n * 64 + d] = sv * (1.0f / 32.0f);
}

// ---------------- attention: one wave per (qpos, head); block = 4 heads of one qpos
// LDS: stage[2048] float4 = 32 KB.
//   selected phase: per-wave 512-f4 slice (32-token K block, XOR-swizzled)
//   window phase  : shared: K chunk swizzled in stage[0:1024], V chunk linear in stage[1024:2048]
// PV loops: p broadcast via __shfl (register), V loads unrolled w/ 4 accumulators.
__global__ __launch_bounds__(256, 4) void attn_kernel(
    const float* __restrict__ q, const float* __restrict__ kbuf, const float* __restrict__ vbuf,
    const float* __restrict__ kc, const float* __restrict__ vc,
    const float* __restrict__ w_gate, const float* __restrict__ b_gate,
    const float* __restrict__ sink, float* __restrict__ mixed)
{
  __shared__ __align__(16) float4 stage[2048];
  __shared__ __align__(16) float shq[4][64];
  __shared__ int shsel[4][16];
  const int lane = threadIdx.x & 63;
  const int wid = threadIdx.x >> 6;
  const int r = blockIdx.x * 4 + wid;   // r = qpos*8 + h; all 4 waves share qpos
  const int qpos = r >> 3, h = r & 7;
  const float scale = 0.125f;

  float qv = q[r * 64 + lane];
  shq[wid][lane] = qv;

  // ---- gate: sigmoid(q @ w_gate + b_gate), normalized ----
  float z0 = qv * ldv(w_gate, lane * 3 + 0);
  float z1 = qv * ldv(w_gate, lane * 3 + 1);
  float z2 = qv * ldv(w_gate, lane * 3 + 2);
  z0 = wave_sum(z0) + ldv(b_gate, 0);
  z1 = wave_sum(z1) + ldv(b_gate, 1);
  z2 = wave_sum(z2) + ldv(b_gate, 2);
  float ga0 = 1.f / (1.f + expf(-z0));
  float ga1 = 1.f / (1.f + expf(-z1));
  float ga2 = 1.f / (1.f + expf(-z2));
  float gs = fmaxf(ga0 + ga1 + ga2, 1e-6f);
  float ginv = 1.f / gs;
  ga0 *= ginv; ga1 *= ginv; ga2 *= ginv;

  const float4* qr = reinterpret_cast<const float4*>(&shq[wid][0]);
  const float4* kg = reinterpret_cast<const float4*>(kbuf);
  const float4* vg = reinterpret_cast<const float4*>(vbuf);
  const float snk = ldv(sink, h);
  const int nv = (qpos + 1) >> 5;  // valid compressed blocks

  // ---- compressed scores (lane = block index) ----
  float sc;
  {
    const float4* kr = reinterpret_cast<const float4*>(kc + lane * 64);
    float d0 = 0.f, d1 = 0.f;
#pragma unroll
    for (int i = 0; i < 16; ++i) {
      float4 a = qr[i], b = kr[i];
      d0 += a.x * b.x + a.z * b.z;
      d1 += a.y * b.y + a.w * b.w;
    }
    sc = (d0 + d1) * scale;
  }

  float comp_out = 0.f;
  if (nv > 0) {
    float scomp = (lane < nv) ? sc : NEGBIG;
    float m = fmaxf(wave_max(scomp), snk);
    float e = (lane < nv) ? expf(sc - m) : 0.f;
    float S = wave_sum(e) + expf(snk - m);
    float pn = e / S;   // zero for lane >= nv
    float c0 = 0.f, c1 = 0.f, c2 = 0.f, c3 = 0.f;
#pragma unroll
    for (int n = 0; n < 64; n += 4) {
      float p0 = __shfl(pn, n + 0, 64);
      float p1 = __shfl(pn, n + 1, 64);
      float p2 = __shfl(pn, n + 2, 64);
      float p3 = __shfl(pn, n + 3, 64);
      c0 += p0 * vc[(n + 0) * 64 + lane];
      c1 += p1 * vc[(n + 1) * 64 + lane];
      c2 += p2 * vc[(n + 2) * 64 + lane];
      c3 += p3 * vc[(n + 3) * 64 + lane];
    }
    comp_out = (c0 + c1) + (c2 + c3);
  }

  // ---- top-16 block selection (emulates jax.lax.top_k tie semantics) ----
  {
    float selv = (lane < nv) ? sc : -FLT_MAX;   // invalid = -FLT_MAX (picked by index order)
#pragma unroll
    for (int it = 0; it < 16; ++it) {
      float bv = selv; int bi = lane;
#pragma unroll
      for (int off = 32; off; off >>= 1) {
        float ov = __shfl_xor(bv, off, 64);
        int oi = __shfl_xor(bi, off, 64);
        if (ov > bv || (ov == bv && oi < bi)) { bv = ov; bi = oi; }
      }
      if (lane == 0) shsel[wid][it] = bi;
      if (lane == bi) selv = -INFINITY;         // removed, never re-picked
    }
  }

  // ---- selected branch: 16 chunks of one 32-token block each ----
  // K staged coalesced into per-wave LDS slice (XOR swizzle); PV on global V,
  // p broadcast by shuffle, 4 accumulator chains.
  float4* slice = stage + wid * 512;
  float M = NEGBIG, S = 0.f, osel = 0.f;
  for (int c = 0; c < 16; ++c) {
    int b = shsel[wid][c];
    int tokbase = b * 32;
#pragma unroll
    for (int j = 0; j < 8; ++j) {
      int g = j * 64 + lane;
      int row = g >> 4, d4 = g & 15;
      slice[(row << 4) | (d4 ^ (row & 7))] = kg[(tokbase + row) * 16 + d4];
    }
    int tok = tokbase + lane;
    bool ok = (lane < 32) && (tok <= qpos);
    float d0 = 0.f, d1 = 0.f;
#pragma unroll
    for (int i = 0; i < 16; ++i) {
      float4 a = qr[i];
      float4 bb = slice[((lane & 31) << 4) | (i ^ (lane & 7))];
      d0 += a.x * bb.x + a.z * bb.z;
      d1 += a.y * bb.y + a.w * bb.w;
    }
    float s = ok ? (d0 + d1) * scale : NEGBIG;
    float Mn = fmaxf(M, wave_max(s));
    float e = ok ? expf(s - Mn) : 0.f;
    float cs = wave_sum(e);
    float corr = expf(M - Mn);
    S = S * corr + cs;
    float a0 = 0.f, a1 = 0.f, a2 = 0.f, a3 = 0.f;
#pragma unroll
    for (int l = 0; l < 32; l += 4) {
      float p0 = __shfl(e, l + 0, 64);
      float p1 = __shfl(e, l + 1, 64);
      float p2 = __shfl(e, l + 2, 64);
      float p3 = __shfl(e, l + 3, 64);
      a0 += p0 * vbuf[(tokbase + l + 0) * 64 + lane];
      a1 += p1 * vbuf[(tokbase + l + 1) * 64 + lane];
      a2 += p2 * vbuf[(tokbase + l + 2) * 64 + lane];
      a3 += p3 * vbuf[(tokbase + l + 3) * 64 + lane];
    }
    osel = osel * corr + ((a0 + a1) + (a2 + a3));
    M = Mn;
  }
  osel /= S;

  // ---- sliding-window branch (window 512, with sink) ----
  // K chunk (swizzled) + V chunk (linear) staged cooperatively, shared by 4 waves.
  float Mw = NEGBIG, Sw = 0.f, osw = 0.f;
  int kstart = qpos - 511; if (kstart < 0) kstart = 0;
  int nch = (qpos - kstart + 64) >> 6;
  float* shv = reinterpret_cast<float*>(stage + 1024);
  for (int c = 0; c < nch; ++c) {
    __syncthreads();   // previous chunk (or selected phase) reads complete
    int base = kstart + c * 64;
#pragma unroll
    for (int j = 0; j < 4; ++j) {
      int g = j * 256 + threadIdx.x;
      int row = g >> 4, d4 = g & 15;
      stage[(row << 4) | (d4 ^ (row & 7))] = kg[(base + row) * 16 + d4];
      stage[1024 + g] = vg[(base + row) * 16 + d4];
    }
    __syncthreads();
    int tok = base + lane;
    bool ok = (tok <= qpos);
    float d0 = 0.f, d1 = 0.f;
#pragma unroll
    for (int i = 0; i < 16; ++i) {
      float4 a = qr[i];
      float4 bb = stage[(lane << 4) | (i ^ (lane & 7))];
      d0 += a.x * bb.x + a.z * bb.z;
      d1 += a.y * bb.y + a.w * bb.w;
    }
    float s = ok ? (d0 + d1) * scale : NEGBIG;
    float Mn = fmaxf(Mw, wave_max(s));
    float e = ok ? expf(s - Mn) : 0.f;
    float cs = wave_sum(e);
    float corr = expf(Mw - Mn);
    Sw = Sw * corr + cs;
    float a0 = 0.f, a1 = 0.f, a2 = 0.f, a3 = 0.f;
#pragma unroll
    for (int l = 0; l < 64; l += 4) {
      float p0 = __shfl(e, l + 0, 64);
      float p1 = __shfl(e, l + 1, 64);
      float p2 = __shfl(e, l + 2, 64);
      float p3 = __shfl(e, l + 3, 64);
      a0 += p0 * shv[((l + 0) << 6) | lane];
      a1 += p1 * shv[((l + 1) << 6) | lane];
      a2 += p2 * shv[((l + 2) << 6) | lane];
      a3 += p3 * shv[((l + 3) << 6) | lane];
    }
    osw = osw * corr + ((a0 + a1) + (a2 + a3));
    Mw = Mn;
  }
  {
    float Mf = fmaxf(Mw, snk);
    float corr = expf(Mw - Mf);
    float Sf = Sw * corr + expf(snk - Mf);
    osw = osw * corr / Sf;
  }

  mixed[r * 64 + lane] = ga0 * comp_out + ga1 * osel + ga2 * osw;
}

// ---------------- launch ----------------
extern "C" void kernel_launch(void* const* d_in, const int* in_sizes, int n_in,
                              void* d_out, int out_size, void* d_ws, size_t ws_size,
                              hipStream_t stream) {
  const float* h      = (const float*)d_in[0];
  const float* w_qc   = (const float*)d_in[1];
  const float* w_qup  = (const float*)d_in[2];
  const float* w_k    = (const float*)d_in[3];
  const float* w_v    = (const float*)d_in[4];
  const float* g_qn   = (const float*)d_in[5];
  const float* g_kn   = (const float*)d_in[6];
  const float* w_gate = (const float*)d_in[7];
  const float* b_gate = (const float*)d_in[8];
  const float* sink   = (const float*)d_in[9];
  const float* wog    = (const float*)d_in[10];
  const float* w_out  = (const float*)d_in[11];
  float* out = (float*)d_out;

  float* ws = (float*)d_ws;
  float* hc = ws;                    // 2048*256
  float* qb = hc + 2048 * 256;       // 2048*512  (t, h, d)
  float* kb = qb + 2048 * 512;       // 2048*64
  float* vb = kb + 2048 * 64;        // 2048*64
  float* kc = vb + 2048 * 64;        // 64*64
  float* vc = kc + 64 * 64;          // 64*64
  float* mx = vc + 64 * 64;          // 2048*512  (t, h, d)
  float* y1 = mx + 2048 * 512;       // 2048*1024

  dim3 blk(256);
  // hc = h @ w_qc
  gemm_tile<float, float, float><<<dim3(4, 32), blk, 0, stream>>>(h, w_qc, hc, 2048, 256, 1024, 1024, 256, 256);
  // q_raw = hc @ w_qup
  gemm_tile<float, float, float><<<dim3(8, 32), blk, 0, stream>>>(hc, w_qup, qb, 2048, 512, 256, 256, 512, 512);
  // k_raw = h @ w_k ; v = h @ w_v
  gemm_tile<float, float, float><<<dim3(1, 32), blk, 0, stream>>>(h, w_k, kb, 2048, 64, 1024, 1024, 64, 64);
  gemm_tile<float, float, float><<<dim3(1, 32), blk, 0, stream>>>(h, w_v, vb, 2048, 64, 1024, 1024, 64, 64);
  // RoPE + RMSNorm
  rope_rms_kernel<<<dim3(4096), blk, 0, stream>>>(qb, g_qn, 16384, 3);
  rope_rms_kernel<<<dim3(512), blk, 0, stream>>>(kb, g_kn, 2048, 0);
  // compressed K/V
  compress_kernel<<<dim3(64), dim3(64), 0, stream>>>(kb, vb, kc, vc);
  // attention (comp + selected + sliding window + gate mix)
  attn_kernel<<<dim3(4096), blk, 0, stream>>>(qb, kb, vb, kc, vc, w_gate, b_gate, sink, mx);
  // grouped projection: y1[:, g*512:(g+1)*512] = mx[:, g*256:(g+1)*256] @ wog[g]
  gemm_tile<float, float, float><<<dim3(8, 32), blk, 0, stream>>>(mx, wog, y1, 2048, 512, 256, 512, 512, 1024);
  gemm_tile<float, float, float><<<dim3(8, 32), blk, 0, stream>>>(mx + 256, wog + 256 * 512, y1 + 512, 2048, 512, 256, 512, 512, 1024);
  // out = y1 @ w_out  (f32 store)
  gemm_tile<float, float, float><<<dim3(16, 32), blk, 0, stream>>>(y1, w_out, out, 2048, 1024, 1024, 1024, 1024, 1024);
}

// Round 9
// 1000.424 us; speedup vs baseline: 1.4178x; 1.4178x over previous
//
#include <hip/hip_runtime.h>
#include <hip/hip_bf16.h>
#include <float.h>
#include <math.h>

typedef __hip_bfloat16 bf16;

#define NEGBIG (-1e30f)

__device__ __forceinline__ float ldv(const bf16* p, int i) { return __bfloat162float(p[i]); }
__device__ __forceinline__ float ldv(const float* p, int i) { return p[i]; }
__device__ __forceinline__ void stv(float* p, int i, float v) { p[i] = v; }
__device__ __forceinline__ void stv(bf16* p, int i, float v) { p[i] = __float2bfloat16(v); }

__device__ __forceinline__ float wave_sum(float v) {
#pragma unroll
  for (int off = 32; off; off >>= 1) v += __shfl_xor(v, off, 64);
  return v;
}
__device__ __forceinline__ float wave_max(float v) {
#pragma unroll
  for (int off = 32; off; off >>= 1) v = fmaxf(v, __shfl_xor(v, off, 64));
  return v;
}

// ---------------- generic tiled GEMM: C(MxN) = A(MxK) @ B(KxN), f32 accum ----
template <typename TA, typename TB, typename TC>
__global__ __launch_bounds__(256) void gemm_tile(
    const TA* __restrict__ A, const TB* __restrict__ B, TC* __restrict__ C,
    int M, int N, int K, int lda, int ldb, int ldc)
{
  __shared__ float As[16][65];
  __shared__ float Bs[16][65];
  const int tid = threadIdx.x;
  const int tx = tid & 15, ty = tid >> 4;
  const int row0 = blockIdx.y * 64, col0 = blockIdx.x * 64;
  float acc[4][4] = {};
  for (int k0 = 0; k0 < K; k0 += 16) {
#pragma unroll
    for (int l = 0; l < 4; ++l) {
      int idx = tid + l * 256;
      int m = idx >> 4, kk = idx & 15;
      As[kk][m] = ldv(A, (row0 + m) * lda + k0 + kk);
      int kk2 = idx >> 6, n = idx & 63;
      Bs[kk2][n] = ldv(B, (k0 + kk2) * ldb + col0 + n);
    }
    __syncthreads();
#pragma unroll
    for (int kk = 0; kk < 16; ++kk) {
      float a[4], b[4];
#pragma unroll
      for (int i = 0; i < 4; ++i) a[i] = As[kk][ty * 4 + i];
#pragma unroll
      for (int j = 0; j < 4; ++j) b[j] = Bs[kk][tx * 4 + j];
#pragma unroll
      for (int i = 0; i < 4; ++i)
#pragma unroll
        for (int j = 0; j < 4; ++j) acc[i][j] += a[i] * b[j];
    }
    __syncthreads();
  }
#pragma unroll
  for (int i = 0; i < 4; ++i)
#pragma unroll
    for (int j = 0; j < 4; ++j)
      stv(C, (row0 + ty * 4 + i) * ldc + col0 + tx * 4 + j, acc[i][j]);
}

// ---------------- RoPE (first 32 dims) + RMSNorm, one wave per 64-dim row ----
__global__ __launch_bounds__(256) void rope_rms_kernel(
    float* __restrict__ x, const float* __restrict__ g, int rows, int posShift)
{
  const int lane = threadIdx.x & 63;
  const int wid = threadIdx.x >> 6;
  const int r = blockIdx.x * 4 + wid;
  if (r >= rows) return;
  const int pos = r >> posShift;
  float val = x[r * 64 + lane];
  float p = __shfl_xor(val, 16, 64);
  float out = val;
  if (lane < 32) {
    int i = lane & 15;
    double ang = (double)pos * pow(10000.0, -(double)i / 16.0);
    float cc = (float)cos(ang), ss = (float)sin(ang);
    out = (lane < 16) ? (val * cc - p * ss) : (p * ss + val * cc);
  }
  float ms = wave_sum(out * out) * (1.0f / 64.0f);
  float rn = rsqrtf(ms + 1e-6f);
  x[r * 64 + lane] = out * rn * ldv(g, lane);
}

// ---------------- block-mean compression: kc/vc (64 blocks x 64 dims) --------
__global__ void compress_kernel(const float* __restrict__ k, const float* __restrict__ v,
                                float* __restrict__ kc, float* __restrict__ vc)
{
  const int n = blockIdx.x;   // block index 0..63
  const int d = threadIdx.x;  // dim 0..63
  float sk = 0.f, sv = 0.f;
  for (int j = 0; j < 32; ++j) {
    sk += k[(n * 32 + j) * 64 + d];
    sv += v[(n * 32 + j) * 64 + d];
  }
  kc[n * 64 + d] = sk * (1.0f / 32.0f);
  vc[n * 64 + d] = sv * (1.0f / 32.0f);
}

// ---------------- attention: one wave per (qpos, head); block = 4 heads of one qpos
// LDS: stage[2048] float4 = 32 KB.
//   selected phase: per-wave 512-f4 slice (32-token K block, XOR-swizzled)
//   window phase  : shared: K chunk swizzled in stage[0:1024], V chunk linear in stage[1024:2048]
// PV loops: p broadcast via __shfl (register), V loads unrolled w/ 4 accumulators.
// NOTE: no second launch_bounds arg — r8 showed (256,4) forces VGPR 64 -> 1.4GB spill traffic.
__global__ __launch_bounds__(256) void attn_kernel(
    const float* __restrict__ q, const float* __restrict__ kbuf, const float* __restrict__ vbuf,
    const float* __restrict__ kc, const float* __restrict__ vc,
    const float* __restrict__ w_gate, const float* __restrict__ b_gate,
    const float* __restrict__ sink, float* __restrict__ mixed)
{
  __shared__ __align__(16) float4 stage[2048];
  __shared__ __align__(16) float shq[4][64];
  __shared__ int shsel[4][16];
  const int lane = threadIdx.x & 63;
  const int wid = threadIdx.x >> 6;
  const int r = blockIdx.x * 4 + wid;   // r = qpos*8 + h; all 4 waves share qpos
  const int qpos = r >> 3, h = r & 7;
  const float scale = 0.125f;

  float qv = q[r * 64 + lane];
  shq[wid][lane] = qv;

  // ---- gate: sigmoid(q @ w_gate + b_gate), normalized ----
  float z0 = qv * ldv(w_gate, lane * 3 + 0);
  float z1 = qv * ldv(w_gate, lane * 3 + 1);
  float z2 = qv * ldv(w_gate, lane * 3 + 2);
  z0 = wave_sum(z0) + ldv(b_gate, 0);
  z1 = wave_sum(z1) + ldv(b_gate, 1);
  z2 = wave_sum(z2) + ldv(b_gate, 2);
  float ga0 = 1.f / (1.f + expf(-z0));
  float ga1 = 1.f / (1.f + expf(-z1));
  float ga2 = 1.f / (1.f + expf(-z2));
  float gs = fmaxf(ga0 + ga1 + ga2, 1e-6f);
  float ginv = 1.f / gs;
  ga0 *= ginv; ga1 *= ginv; ga2 *= ginv;

  const float4* qr = reinterpret_cast<const float4*>(&shq[wid][0]);
  const float4* kg = reinterpret_cast<const float4*>(kbuf);
  const float4* vg = reinterpret_cast<const float4*>(vbuf);
  const float snk = ldv(sink, h);
  const int nv = (qpos + 1) >> 5;  // valid compressed blocks

  // ---- compressed scores (lane = block index) ----
  float sc;
  {
    const float4* kr = reinterpret_cast<const float4*>(kc + lane * 64);
    float d0 = 0.f, d1 = 0.f;
#pragma unroll
    for (int i = 0; i < 16; ++i) {
      float4 a = qr[i], b = kr[i];
      d0 += a.x * b.x + a.z * b.z;
      d1 += a.y * b.y + a.w * b.w;
    }
    sc = (d0 + d1) * scale;
  }

  float comp_out = 0.f;
  if (nv > 0) {
    float scomp = (lane < nv) ? sc : NEGBIG;
    float m = fmaxf(wave_max(scomp), snk);
    float e = (lane < nv) ? expf(sc - m) : 0.f;
    float S = wave_sum(e) + expf(snk - m);
    float pn = e / S;   // zero for lane >= nv
    float c0 = 0.f, c1 = 0.f, c2 = 0.f, c3 = 0.f;
#pragma unroll
    for (int n = 0; n < 64; n += 4) {
      float p0 = __shfl(pn, n + 0, 64);
      float p1 = __shfl(pn, n + 1, 64);
      float p2 = __shfl(pn, n + 2, 64);
      float p3 = __shfl(pn, n + 3, 64);
      c0 += p0 * vc[(n + 0) * 64 + lane];
      c1 += p1 * vc[(n + 1) * 64 + lane];
      c2 += p2 * vc[(n + 2) * 64 + lane];
      c3 += p3 * vc[(n + 3) * 64 + lane];
    }
    comp_out = (c0 + c1) + (c2 + c3);
  }

  // ---- top-16 block selection (emulates jax.lax.top_k tie semantics) ----
  {
    float selv = (lane < nv) ? sc : -FLT_MAX;   // invalid = -FLT_MAX (picked by index order)
#pragma unroll
    for (int it = 0; it < 16; ++it) {
      float bv = selv; int bi = lane;
#pragma unroll
      for (int off = 32; off; off >>= 1) {
        float ov = __shfl_xor(bv, off, 64);
        int oi = __shfl_xor(bi, off, 64);
        if (ov > bv || (ov == bv && oi < bi)) { bv = ov; bi = oi; }
      }
      if (lane == 0) shsel[wid][it] = bi;
      if (lane == bi) selv = -INFINITY;         // removed, never re-picked
    }
  }

  // ---- selected branch: 16 chunks of one 32-token block each ----
  // K staged coalesced into per-wave LDS slice (XOR swizzle); PV on global V,
  // p broadcast by shuffle, 4 accumulator chains.
  float4* slice = stage + wid * 512;
  float M = NEGBIG, S = 0.f, osel = 0.f;
  for (int c = 0; c < 16; ++c) {
    int b = shsel[wid][c];
    int tokbase = b * 32;
#pragma unroll
    for (int j = 0; j < 8; ++j) {
      int g = j * 64 + lane;
      int row = g >> 4, d4 = g & 15;
      slice[(row << 4) | (d4 ^ (row & 7))] = kg[(tokbase + row) * 16 + d4];
    }
    int tok = tokbase + lane;
    bool ok = (lane < 32) && (tok <= qpos);
    float d0 = 0.f, d1 = 0.f;
#pragma unroll
    for (int i = 0; i < 16; ++i) {
      float4 a = qr[i];
      float4 bb = slice[((lane & 31) << 4) | (i ^ (lane & 7))];
      d0 += a.x * bb.x + a.z * bb.z;
      d1 += a.y * bb.y + a.w * bb.w;
    }
    float s = ok ? (d0 + d1) * scale : NEGBIG;
    float Mn = fmaxf(M, wave_max(s));
    float e = ok ? expf(s - Mn) : 0.f;
    float cs = wave_sum(e);
    float corr = expf(M - Mn);
    S = S * corr + cs;
    float a0 = 0.f, a1 = 0.f, a2 = 0.f, a3 = 0.f;
#pragma unroll
    for (int l = 0; l < 32; l += 4) {
      float p0 = __shfl(e, l + 0, 64);
      float p1 = __shfl(e, l + 1, 64);
      float p2 = __shfl(e, l + 2, 64);
      float p3 = __shfl(e, l + 3, 64);
      a0 += p0 * vbuf[(tokbase + l + 0) * 64 + lane];
      a1 += p1 * vbuf[(tokbase + l + 1) * 64 + lane];
      a2 += p2 * vbuf[(tokbase + l + 2) * 64 + lane];
      a3 += p3 * vbuf[(tokbase + l + 3) * 64 + lane];
    }
    osel = osel * corr + ((a0 + a1) + (a2 + a3));
    M = Mn;
  }
  osel /= S;

  // ---- sliding-window branch (window 512, with sink) ----
  // K chunk (swizzled) + V chunk (linear) staged cooperatively, shared by 4 waves.
  float Mw = NEGBIG, Sw = 0.f, osw = 0.f;
  int kstart = qpos - 511; if (kstart < 0) kstart = 0;
  int nch = (qpos - kstart + 64) >> 6;
  float* shv = reinterpret_cast<float*>(stage + 1024);
  for (int c = 0; c < nch; ++c) {
    __syncthreads();   // previous chunk (or selected phase) reads complete
    int base = kstart + c * 64;
#pragma unroll
    for (int j = 0; j < 4; ++j) {
      int g = j * 256 + threadIdx.x;
      int row = g >> 4, d4 = g & 15;
      stage[(row << 4) | (d4 ^ (row & 7))] = kg[(base + row) * 16 + d4];
      stage[1024 + g] = vg[(base + row) * 16 + d4];
    }
    __syncthreads();
    int tok = base + lane;
    bool ok = (tok <= qpos);
    float d0 = 0.f, d1 = 0.f;
#pragma unroll
    for (int i = 0; i < 16; ++i) {
      float4 a = qr[i];
      float4 bb = stage[(lane << 4) | (i ^ (lane & 7))];
      d0 += a.x * bb.x + a.z * bb.z;
      d1 += a.y * bb.y + a.w * bb.w;
    }
    float s = ok ? (d0 + d1) * scale : NEGBIG;
    float Mn = fmaxf(Mw, wave_max(s));
    float e = ok ? expf(s - Mn) : 0.f;
    float cs = wave_sum(e);
    float corr = expf(Mw - Mn);
    Sw = Sw * corr + cs;
    float a0 = 0.f, a1 = 0.f, a2 = 0.f, a3 = 0.f;
#pragma unroll
    for (int l = 0; l < 64; l += 4) {
      float p0 = __shfl(e, l + 0, 64);
      float p1 = __shfl(e, l + 1, 64);
      float p2 = __shfl(e, l + 2, 64);
      float p3 = __shfl(e, l + 3, 64);
      a0 += p0 * shv[((l + 0) << 6) | lane];
      a1 += p1 * shv[((l + 1) << 6) | lane];
      a2 += p2 * shv[((l + 2) << 6) | lane];
      a3 += p3 * shv[((l + 3) << 6) | lane];
    }
    osw = osw * corr + ((a0 + a1) + (a2 + a3));
    Mw = Mn;
  }
  {
    float Mf = fmaxf(Mw, snk);
    float corr = expf(Mw - Mf);
    float Sf = Sw * corr + expf(snk - Mf);
    osw = osw * corr / Sf;
  }

  mixed[r * 64 + lane] = ga0 * comp_out + ga1 * osel + ga2 * osw;
}

// ---------------- launch ----------------
extern "C" void kernel_launch(void* const* d_in, const int* in_sizes, int n_in,
                              void* d_out, int out_size, void* d_ws, size_t ws_size,
                              hipStream_t stream) {
  const float* h      = (const float*)d_in[0];
  const float* w_qc   = (const float*)d_in[1];
  const float* w_qup  = (const float*)d_in[2];
  const float* w_k    = (const float*)d_in[3];
  const float* w_v    = (const float*)d_in[4];
  const float* g_qn   = (const float*)d_in[5];
  const float* g_kn   = (const float*)d_in[6];
  const float* w_gate = (const float*)d_in[7];
  const float* b_gate = (const float*)d_in[8];
  const float* sink   = (const float*)d_in[9];
  const float* wog    = (const float*)d_in[10];
  const float* w_out  = (const float*)d_in[11];
  float* out = (float*)d_out;

  float* ws = (float*)d_ws;
  float* hc = ws;                    // 2048*256
  float* qb = hc + 2048 * 256;       // 2048*512  (t, h, d)
  float* kb = qb + 2048 * 512;       // 2048*64
  float* vb = kb + 2048 * 64;        // 2048*64
  float* kc = vb + 2048 * 64;        // 64*64
  float* vc = kc + 64 * 64;          // 64*64
  float* mx = vc + 64 * 64;          // 2048*512  (t, h, d)
  float* y1 = mx + 2048 * 512;       // 2048*1024

  dim3 blk(256);
  // hc = h @ w_qc
  gemm_tile<float, float, float><<<dim3(4, 32), blk, 0, stream>>>(h, w_qc, hc, 2048, 256, 1024, 1024, 256, 256);
  // q_raw = hc @ w_qup
  gemm_tile<float, float, float><<<dim3(8, 32), blk, 0, stream>>>(hc, w_qup, qb, 2048, 512, 256, 256, 512, 512);
  // k_raw = h @ w_k ; v = h @ w_v
  gemm_tile<float, float, float><<<dim3(1, 32), blk, 0, stream>>>(h, w_k, kb, 2048, 64, 1024, 1024, 64, 64);
  gemm_tile<float, float, float><<<dim3(1, 32), blk, 0, stream>>>(h, w_v, vb, 2048, 64, 1024, 1024, 64, 64);
  // RoPE + RMSNorm
  rope_rms_kernel<<<dim3(4096), blk, 0, stream>>>(qb, g_qn, 16384, 3);
  rope_rms_kernel<<<dim3(512), blk, 0, stream>>>(kb, g_kn, 2048, 0);
  // compressed K/V
  compress_kernel<<<dim3(64), dim3(64), 0, stream>>>(kb, vb, kc, vc);
  // attention (comp + selected + sliding window + gate mix)
  attn_kernel<<<dim3(4096), blk, 0, stream>>>(qb, kb, vb, kc, vc, w_gate, b_gate, sink, mx);
  // grouped projection: y1[:, g*512:(g+1)*512] = mx[:, g*256:(g+1)*256] @ wog[g]
  gemm_tile<float, float, float><<<dim3(8, 32), blk, 0, stream>>>(mx, wog, y1, 2048, 512, 256, 512, 512, 1024);
  gemm_tile<float, float, float><<<dim3(8, 32), blk, 0, stream>>>(mx + 256, wog + 256 * 512, y1 + 512, 2048, 512, 256, 512, 512, 1024);
  // out = y1 @ w_out  (f32 store)
  gemm_tile<float, float, float><<<dim3(16, 32), blk, 0, stream>>>(y1, w_out, out, 2048, 1024, 1024, 1024, 1024, 1024);
}